// Round 1
// baseline (117.618 us; speedup 1.0000x reference)
//
#include <hip/hip_runtime.h>
#include <hip/hip_bf16.h>

// SimilarityLayer: out[e,q,w,n,m] = <p[e,w,:,n], q[e,q,:,m]> / (|p||q| + 1e-8)
// E=8 W=5 C=640 N=49 Q=75. Batched GEMM per (e,q): [245 x 640] x [640 x 49].
// bf16 MFMA 16x16x32, fp32 norms fused into staging.

#define E_CNT 8
#define W_CNT 5
#define C_CNT 640
#define N_CNT 49
#define Q_CNT 75

typedef __attribute__((ext_vector_type(8))) short bf16x8;
typedef __attribute__((ext_vector_type(4))) float f32x4;

static __device__ __forceinline__ short f2bf(float f) {
    __hip_bfloat16 h = __float2bfloat16(f);
    return *reinterpret_cast<short*>(&h);
}

__global__ __launch_bounds__(256, 2)
void sim_mfma_kernel(const float* __restrict__ proto,
                     const float* __restrict__ query,
                     float* __restrict__ out)
{
    // A: [256 rows(nw)][64 k] bf16, row = 128 B = 8 granules of 16 B,
    // granule XOR-swizzled by (row&7) -> ds_read_b128 frags ~conflict-free.
    __shared__ __align__(16) unsigned char Abuf[256 * 128];
    __shared__ __align__(16) unsigned char Bbuf[64 * 128];
    __shared__ float sp[256];   // sum of squares, proto cols (nw)
    __shared__ float sq[64];    // sum of squares, query cols (m)

    const int t   = threadIdx.x;
    const int blk = blockIdx.x;
    const int e   = blk / Q_CNT;
    const int q   = blk - e * Q_CNT;

    const float* __restrict__ pbase = proto + (size_t)e * (W_CNT * C_CNT * N_CNT);
    const float* __restrict__ qbase = query + ((size_t)e * Q_CNT + q) * (C_CNT * N_CNT);

    sp[t] = 0.f;
    if (t < 64) sq[t] = 0.f;

    f32x4 acc[4][4];
    #pragma unroll
    for (int i = 0; i < 4; ++i)
        #pragma unroll
        for (int j = 0; j < 4; ++j)
            acc[i][j] = (f32x4){0.f, 0.f, 0.f, 0.f};

    __syncthreads();  // sp/sq zeroed before first atomicAdd

    const int wv   = t >> 6;   // wave 0..3
    const int ln   = t & 63;
    const int lrow = ln & 15;  // fragment non-K index
    const int lk   = ln >> 4;  // fragment K-group

    for (int kc = 0; kc < 10; ++kc) {
        const int k0 = kc * 64;

        // ---- stage: fp32 global -> bf16 LDS (+ fused sum-of-squares) ----
        // A slots: s = kb*245 + nw (kb in [0,8), 8 consecutive k each)
        // B slots: s = 1960 + kb*49 + m
        for (int s = t; s < 1960 + 392; s += 256) {
            if (s < 1960) {
                const int kb = s / 245;
                const int nw = s - kb * 245;
                const int w  = nw / 49;
                const int n  = nw - w * 49;
                const float* g = pbase + ((size_t)w * C_CNT + (k0 + kb * 8)) * N_CNT + n;
                float v[8];
                #pragma unroll
                for (int j = 0; j < 8; ++j) v[j] = g[(size_t)j * N_CNT];
                float ss = 0.f;
                bf16x8 pk;
                #pragma unroll
                for (int j = 0; j < 8; ++j) { ss += v[j] * v[j]; pk[j] = f2bf(v[j]); }
                *reinterpret_cast<bf16x8*>(Abuf + nw * 128 + ((kb ^ (nw & 7)) << 4)) = pk;
                atomicAdd(&sp[nw], ss);
            } else {
                const int s2 = s - 1960;
                const int kb = s2 / 49;
                const int m  = s2 - kb * 49;
                const float* g = qbase + (size_t)(k0 + kb * 8) * N_CNT + m;
                float v[8];
                #pragma unroll
                for (int j = 0; j < 8; ++j) v[j] = g[(size_t)j * N_CNT];
                float ss = 0.f;
                bf16x8 pk;
                #pragma unroll
                for (int j = 0; j < 8; ++j) { ss += v[j] * v[j]; pk[j] = f2bf(v[j]); }
                *reinterpret_cast<bf16x8*>(Bbuf + m * 128 + ((kb ^ (m & 7)) << 4)) = pk;
                atomicAdd(&sq[m], ss);
            }
        }
        __syncthreads();

        // ---- compute: wave wv owns n-tiles [4wv..4wv+3] x all 4 m-tiles ----
        #pragma unroll
        for (int ks = 0; ks < 2; ++ks) {
            bf16x8 af[4], bf[4];
            #pragma unroll
            for (int i = 0; i < 4; ++i) {
                const int nw = (wv * 4 + i) * 16 + lrow;
                const int gr = (ks * 4 + lk) ^ (nw & 7);
                af[i] = *reinterpret_cast<const bf16x8*>(Abuf + nw * 128 + gr * 16);
            }
            #pragma unroll
            for (int j = 0; j < 4; ++j) {
                const int m  = j * 16 + lrow;
                const int gr = (ks * 4 + lk) ^ (m & 7);
                bf[j] = *reinterpret_cast<const bf16x8*>(Bbuf + m * 128 + gr * 16);
            }
            #pragma unroll
            for (int i = 0; i < 4; ++i)
                #pragma unroll
                for (int j = 0; j < 4; ++j)
                    acc[i][j] = __builtin_amdgcn_mfma_f32_16x16x32_bf16(
                        af[i], bf[j], acc[i][j], 0, 0, 0);
        }
        __syncthreads();
    }

    // ---- epilogue: divide by (|p| * |q| + 1e-8), masked write ----
    float nq[4];
    #pragma unroll
    for (int j = 0; j < 4; ++j) {
        const int m = j * 16 + lrow;
        nq[j] = (m < N_CNT) ? sqrtf(sq[m]) : 1.f;
    }
    float* obase = out + (size_t)((e * Q_CNT + q)) * (W_CNT * N_CNT * N_CNT);
    #pragma unroll
    for (int i = 0; i < 4; ++i) {
        #pragma unroll
        for (int r = 0; r < 4; ++r) {
            const int nw = (wv * 4 + i) * 16 + lk * 4 + r;  // D row = (lane>>4)*4 + reg
            if (nw < W_CNT * N_CNT) {
                const int w = nw / 49;
                const int n = nw - w * 49;
                const float np_ = sqrtf(sp[nw]);
                float* orow = obase + ((size_t)w * N_CNT + n) * N_CNT;
                #pragma unroll
                for (int j = 0; j < 4; ++j) {
                    const int m = j * 16 + lrow;  // D col = lane&15
                    if (m < N_CNT) {
                        orow[m] = acc[i][j][r] / (np_ * nq[j] + 1e-8f);
                    }
                }
            }
        }
    }
}

extern "C" void kernel_launch(void* const* d_in, const int* in_sizes, int n_in,
                              void* d_out, int out_size, void* d_ws, size_t ws_size,
                              hipStream_t stream)
{
    const float* proto = (const float*)d_in[0];
    const float* query = (const float*)d_in[1];
    float* out = (float*)d_out;
    dim3 grid(E_CNT * Q_CNT);  // 600 blocks: one per (e, q)
    dim3 block(256);
    hipLaunchKernelGGL(sim_mfma_kernel, grid, block, 0, stream, proto, query, out);
}

// Round 2
// 83.725 us; speedup vs baseline: 1.4048x; 1.4048x over previous
//
#include <hip/hip_runtime.h>
#include <hip/hip_bf16.h>

// SimilarityLayer: out[e,q,w,n,m] = <p[e,w,:,n], q[e,q,:,m]> / (|p||q| + 1e-8)
// E=8 W=5 C=640 N=49 Q=75. Batched GEMM per (e,q): [245 x 640] x [640 x 49].
// bf16 MFMA 16x16x32, fp32 norms fused into staging.
// R2: 512 threads (8 waves), static unrolled slot staging (batched loads),
//     register prefetch of next K-chunk overlapped with MFMA (T14),
//     register norm accumulation (one atomicAdd per slot at end).

#define E_CNT 8
#define W_CNT 5
#define C_CNT 640
#define N_CNT 49
#define Q_CNT 75

typedef __attribute__((ext_vector_type(8))) short bf16x8;
typedef __attribute__((ext_vector_type(4))) float f32x4;

static __device__ __forceinline__ short f2bf(float f) {
    __hip_bfloat16 h = __float2bfloat16(f);
    return *reinterpret_cast<short*>(&h);
}

struct SMem {
    unsigned char A[256 * 128];  // [row nw][8 granules x16B], granule ^= row&7
    unsigned char B[64 * 128];   // [row m ][8 granules x16B], granule ^= row&7
    float ns[320];               // 0..244: |p|^2 per nw ; 256+m: |q|^2 per m
};

__global__ __launch_bounds__(512, 4)
void sim_mfma_kernel(const float* __restrict__ proto,
                     const float* __restrict__ query,
                     float* __restrict__ out)
{
    __shared__ SMem sm;
    const int t = threadIdx.x;
    const int e = blockIdx.x / Q_CNT;
    const int q = blockIdx.x - e * Q_CNT;

    const float* __restrict__ pbase = proto + (size_t)e * (W_CNT * C_CNT * N_CNT);
    const float* __restrict__ qbase = query + ((size_t)e * Q_CNT + q) * (C_CNT * N_CNT);
    unsigned char* lds = (unsigned char*)&sm;

    // zero norm accumulators + never-staged LDS rows (A rows 245..255, B rows 49..63)
    if (t < 320) sm.ns[t] = 0.f;
    if (t < 208) {
        if (t < 88) *reinterpret_cast<f32x4*>(sm.A + 245 * 128 + t * 16) = (f32x4){0.f, 0.f, 0.f, 0.f};
        else        *reinterpret_cast<f32x4*>(sm.B + 49 * 128 + (t - 88) * 16) = (f32x4){0.f, 0.f, 0.f, 0.f};
    }

    // ---- static slot assignment: slot s = t + i*512 ----
    // s < 1960: A slot (kb = s/245, nw = s%245); else B slot (s2 = s-1960, kb=s2/49, m=s2%49)
    // slots 0..3 always valid (max s = 2047); slot 4 valid iff t < 304 (s = 2048..2351)
    const int nslot5 = (t < 304);
    const float* gp[5];
    int offidx[5];  // ldsByteOff (16b) | normIdx << 16
    #pragma unroll
    for (int i = 0; i < 5; ++i) {
        gp[i] = pbase; offidx[i] = 0;
        if (i < 4 || nslot5) {
            const int s = t + i * 512;
            if (s < 1960) {
                const int kb = s / 245, nw = s - kb * 245;
                const int w = nw / 49, n = nw - w * 49;
                gp[i] = pbase + ((size_t)w * C_CNT + kb * 8) * N_CNT + n;
                offidx[i] = (nw * 128 + ((kb ^ (nw & 7)) << 4)) | (nw << 16);
            } else {
                const int s2 = s - 1960;
                const int kb = s2 / 49, m = s2 - kb * 49;
                gp[i] = qbase + (size_t)(kb * 8) * N_CNT + m;
                offidx[i] = (32768 + m * 128 + ((kb ^ (m & 7)) << 4)) | ((256 + m) << 16);
            }
        }
    }

    float v[5][8];
    float ss[5] = {0.f, 0.f, 0.f, 0.f, 0.f};

    // prologue: issue loads for kc=0 (all batched)
    #pragma unroll
    for (int i = 0; i < 4; ++i)
        #pragma unroll
        for (int j = 0; j < 8; ++j) v[i][j] = gp[i][(size_t)j * N_CNT];
    if (nslot5)
        #pragma unroll
        for (int j = 0; j < 8; ++j) v[4][j] = gp[4][(size_t)j * N_CNT];

    f32x4 acc[2][4];
    #pragma unroll
    for (int i = 0; i < 2; ++i)
        #pragma unroll
        for (int j = 0; j < 4; ++j) acc[i][j] = (f32x4){0.f, 0.f, 0.f, 0.f};

    const int wv = t >> 6;
    const int ln = t & 63;
    const int lrow = ln & 15;  // fragment non-K index (D col)
    const int lk = ln >> 4;    // fragment K-group

    for (int kc = 0; kc < 10; ++kc) {
        // ---- convert + write current chunk ----
        #pragma unroll
        for (int i = 0; i < 5; ++i) {
            if (i < 4 || nslot5) {
                bf16x8 pk;
                float s8 = 0.f;
                #pragma unroll
                for (int j = 0; j < 8; ++j) { const float f = v[i][j]; s8 += f * f; pk[j] = f2bf(f); }
                ss[i] += s8;
                *reinterpret_cast<bf16x8*>(lds + (offidx[i] & 0xFFFF)) = pk;
            }
        }
        __syncthreads();

        // ---- issue next chunk's loads (vmcnt wait lands after MFMA below) ----
        if (kc < 9) {
            #pragma unroll
            for (int i = 0; i < 4; ++i) {
                gp[i] += 64 * N_CNT;
                #pragma unroll
                for (int j = 0; j < 8; ++j) v[i][j] = gp[i][(size_t)j * N_CNT];
            }
            if (nslot5) {
                gp[4] += 64 * N_CNT;
                #pragma unroll
                for (int j = 0; j < 8; ++j) v[4][j] = gp[4][(size_t)j * N_CNT];
            }
        }

        // ---- MFMA: wave wv owns i-tiles {2wv, 2wv+1} x 4 m-tiles ----
        #pragma unroll
        for (int ks = 0; ks < 2; ++ks) {
            bf16x8 af[2], bfr[4];
            #pragma unroll
            for (int i = 0; i < 2; ++i) {
                const int row = (wv * 2 + i) * 16 + lrow;
                const int gr = (ks * 4 + lk) ^ (row & 7);
                af[i] = *reinterpret_cast<const bf16x8*>(lds + row * 128 + gr * 16);
            }
            #pragma unroll
            for (int j = 0; j < 4; ++j) {
                const int m = j * 16 + lrow;
                const int gr = (ks * 4 + lk) ^ (m & 7);
                bfr[j] = *reinterpret_cast<const bf16x8*>(lds + 32768 + m * 128 + gr * 16);
            }
            #pragma unroll
            for (int i = 0; i < 2; ++i)
                #pragma unroll
                for (int j = 0; j < 4; ++j)
                    acc[i][j] = __builtin_amdgcn_mfma_f32_16x16x32_bf16(
                        af[i], bfr[j], acc[i][j], 0, 0, 0);
        }
        __syncthreads();
    }

    // ---- norms: one atomicAdd per slot ----
    #pragma unroll
    for (int i = 0; i < 5; ++i)
        if (i < 4 || nslot5)
            atomicAdd(&sm.ns[offidx[i] >> 16], ss[i]);
    __syncthreads();

    // ---- epilogue: divide by (|p||q| + 1e-8), masked write ----
    float nq[4];
    #pragma unroll
    for (int j = 0; j < 4; ++j) {
        const int m = j * 16 + lrow;
        nq[j] = (m < N_CNT) ? sqrtf(sm.ns[256 + m]) : 1.f;
    }
    float* obase = out + (size_t)(e * Q_CNT + q) * (W_CNT * N_CNT * N_CNT);
    #pragma unroll
    for (int i = 0; i < 2; ++i) {
        #pragma unroll
        for (int r = 0; r < 4; ++r) {
            const int nw = (wv * 2 + i) * 16 + lk * 4 + r;  // D row = (lane>>4)*4 + reg
            if (nw < W_CNT * N_CNT) {
                const int w = nw / 49;
                const int n = nw - w * 49;
                const float np_ = sqrtf(sm.ns[nw]);
                float* orow = obase + ((size_t)w * N_CNT + n) * N_CNT;
                #pragma unroll
                for (int j = 0; j < 4; ++j) {
                    const int m = j * 16 + lrow;  // D col = lane&15
                    if (m < N_CNT) orow[m] = acc[i][j][r] / (np_ * nq[j] + 1e-8f);
                }
            }
        }
    }
}

extern "C" void kernel_launch(void* const* d_in, const int* in_sizes, int n_in,
                              void* d_out, int out_size, void* d_ws, size_t ws_size,
                              hipStream_t stream)
{
    const float* proto = (const float*)d_in[0];
    const float* query = (const float*)d_in[1];
    float* out = (float*)d_out;
    dim3 grid(E_CNT * Q_CNT);  // 600 blocks: one per (e, q)
    dim3 block(512);
    hipLaunchKernelGGL(sim_mfma_kernel, grid, block, 0, stream, proto, query, out);
}

// Round 3
// 40.782 us; speedup vs baseline: 2.8841x; 2.0530x over previous
//
#include <hip/hip_runtime.h>
#include <hip/hip_bf16.h>

// SimilarityLayer: out[e,q,w,n,m] = <p[e,w,:,n], q[e,q,:,m]> / (|p||q| + 1e-8)
// E=8 W=5 C=640 N=49 Q=75.  Per e: GEMM [245 x 640] x [640 x 3675].
// R3: prep kernel converts proto -> pre-swizzled bf16 A-image in ws (once, not 75x)
//     + per-chunk partial row norms. GEMM: 232 blocks (e x 128-col q-tile),
//     A staged via global_load_lds(16B) from the swizzled image, B (query)
//     staged fp32->bf16 in-kernel (each column staged exactly once grid-wide),
//     one barrier per K-chunk, double-buffered LDS, q-norms fused.

#define E_CNT 8
#define W_CNT 5
#define C_CNT 640
#define N_CNT 49
#define Q_CNT 75
#define QM_TOT (Q_CNT * N_CNT)      // 3675
#define MROWS (W_CNT * N_CNT)       // 245
#define NTILES 29                   // ceil(3675/128)
#define ASW_BLK 32768               // 256 rows x 128 B per (e, chunk)
#define ASW_SIZE (E_CNT * 10 * ASW_BLK)
#define PN_OFF ASW_SIZE
#define PN_PART_BYTES (E_CNT * 10 * MROWS * 4)
#define WS_NEEDED ((size_t)(PN_OFF + PN_PART_BYTES))

// GEMM LDS layout (dynamic):
#define AB_OFF 0                    // 2 x 32768
#define B_OFF 65536                 // 2 x 16384
#define QN_OFF 98304                // 128 f32
#define PNL_OFF 98816               // 245 f32
#define SM_BYTES 99840

typedef __attribute__((ext_vector_type(8))) short bf16x8;
typedef __attribute__((ext_vector_type(4))) float f32x4;

static __device__ __forceinline__ short f2bf(float f) {
    __hip_bfloat16 h = __float2bfloat16(f);
    return *reinterpret_cast<short*>(&h);
}

static __device__ __forceinline__ void gload16(const void* g, void* l) {
    __builtin_amdgcn_global_load_lds(
        (const __attribute__((address_space(1))) void*)g,
        (__attribute__((address_space(3))) void*)l, 16, 0, 0);
}

// ---------------- prep: proto -> swizzled bf16 A image + partial norms -------
__global__ __launch_bounds__(256, 4)
void prep_kernel(const float* __restrict__ proto,
                 unsigned char* __restrict__ asw,
                 float* __restrict__ pn_part)
{
    __shared__ float pns[MROWS];
    const int b = blockIdx.x;
    const int e = b / 10, cc = b % 10;
    const float* pbase = proto + (size_t)e * (W_CNT * C_CNT * N_CNT);
    unsigned char* abase = asw + (size_t)(e * 10 + cc) * ASW_BLK;
    const int t = threadIdx.x;
    if (t < MROWS) pns[t] = 0.f;
    __syncthreads();

    #pragma unroll
    for (int i = 0; i < 8; ++i) {
        const int s = t + i * 256;          // slot = kb*245 + nw (kb-major -> coalesced)
        if (s < 8 * MROWS) {
            const int kb = s / MROWS;
            const int nw = s - kb * MROWS;
            const int w = nw / N_CNT, n = nw - w * N_CNT;
            const float* g = pbase + ((size_t)(w * C_CNT + cc * 64 + kb * 8)) * N_CNT + n;
            float vv[8];
            #pragma unroll
            for (int j = 0; j < 8; ++j) vv[j] = g[(size_t)j * N_CNT];
            float ss = 0.f;
            bf16x8 pk;
            #pragma unroll
            for (int j = 0; j < 8; ++j) { const float f = vv[j]; ss += f * f; pk[j] = f2bf(f); }
            *reinterpret_cast<bf16x8*>(abase + nw * 128 + ((kb ^ (nw & 7)) << 4)) = pk;
            atomicAdd(&pns[nw], ss);
        } else {
            // zero-pad rows 245..255 (all 8 granules)
            const int x = s - 8 * MROWS;    // 0..87
            const int nw = MROWS + (x >> 3), kb = x & 7;
            *reinterpret_cast<bf16x8*>(abase + nw * 128 + ((kb ^ (nw & 7)) << 4)) =
                (bf16x8){0, 0, 0, 0, 0, 0, 0, 0};
        }
    }
    __syncthreads();
    if (t < MROWS) pn_part[(size_t)(e * 10 + cc) * MROWS + t] = pns[t];
}

// ---------------- GEMM: [256 x 640] x [640 x 128] per block ------------------
__global__ __launch_bounds__(512, 2)
void gemm_kernel(const float* __restrict__ query,
                 const unsigned char* __restrict__ asw,
                 const float* __restrict__ pn_part,
                 float* __restrict__ out)
{
    extern __shared__ unsigned char sm[];
    const int b = blockIdx.x;
    const int e = b / NTILES, jt = b - e * NTILES;
    const int qm0 = jt * 128;
    const int t = threadIdx.x;
    const int wv = t >> 6, ln = t & 63;
    const int lrow = ln & 15, lk = ln >> 4;
    const int wm = wv >> 1, wn = wv & 1;   // wave tile: rows [wm*64,+64) x cols [wn*64,+64)

    float* qn = (float*)(sm + QN_OFF);
    float* pnl = (float*)(sm + PNL_OFF);
    if (t < 128) qn[t] = 0.f;

    // B staging: thread owns row r = t&127 (fixed), granules kb0 and kb0+4
    const int r = t & 127;
    const int kb0 = t >> 7;                 // 0..3
    const int qm = qm0 + r;
    const bool valid = qm < QM_TOT;
    const int q = valid ? (qm / N_CNT) : 0;
    const int m = qm - q * N_CNT;
    const float* qsrc = query + ((size_t)(e * Q_CNT + q) * C_CNT) * N_CNT + m;
    const int bo0 = r * 128 + (((kb0)     ^ (r & 7)) << 4);
    const int bo1 = r * 128 + (((kb0 + 4) ^ (r & 7)) << 4);

    const unsigned char* agl = asw + (size_t)(e * 10) * ASW_BLK;

    float vb[2][8];
    float ss_tot = 0.f;

    f32x4 acc[4][4];
    #pragma unroll
    for (int i = 0; i < 4; ++i)
        #pragma unroll
        for (int j = 0; j < 4; ++j) acc[i][j] = (f32x4){0.f, 0.f, 0.f, 0.f};

#define A_ISSUE(cc, buf) do {                                                   \
    const unsigned char* ag_ = agl + (size_t)(cc) * ASW_BLK;                    \
    _Pragma("unroll")                                                           \
    for (int i_ = 0; i_ < 4; ++i_)                                              \
        gload16(ag_ + (t + i_ * 512) * 16, sm + (buf) * 32768 + (t + i_ * 512) * 16); \
} while (0)

#define B_ISSUE(cc) do {                                                        \
    _Pragma("unroll")                                                           \
    for (int i_ = 0; i_ < 2; ++i_) {                                            \
        const size_t co_ = (size_t)((cc) * 64 + (kb0 + i_ * 4) * 8) * N_CNT;    \
        _Pragma("unroll")                                                       \
        for (int j_ = 0; j_ < 8; ++j_)                                          \
            vb[i_][j_] = valid ? qsrc[co_ + (size_t)j_ * N_CNT] : 0.f;          \
    }                                                                           \
} while (0)

#define B_WRITE(buf) do {                                                       \
    _Pragma("unroll")                                                           \
    for (int i_ = 0; i_ < 2; ++i_) {                                            \
        bf16x8 pk_; float s8_ = 0.f;                                            \
        _Pragma("unroll")                                                       \
        for (int j_ = 0; j_ < 8; ++j_) {                                        \
            const float f_ = vb[i_][j_]; s8_ += f_ * f_; pk_[j_] = f2bf(f_);    \
        }                                                                       \
        ss_tot += s8_;                                                          \
        *reinterpret_cast<bf16x8*>(sm + B_OFF + (buf) * 16384 + (i_ ? bo1 : bo0)) = pk_; \
    }                                                                           \
} while (0)

    // prologue: stage chunk 0
    A_ISSUE(0, 0);
    B_ISSUE(0);
    B_WRITE(0);
    __syncthreads();

    for (int cc = 0; cc < 10; ++cc) {
        const int cur = cc & 1, nxt = cur ^ 1;
        if (cc < 9) { A_ISSUE(cc + 1, nxt); B_ISSUE(cc + 1); }

        // MFMA on buffers [cur]
        {
            const unsigned char* Ab = sm + cur * 32768;
            const unsigned char* Bb = sm + B_OFF + cur * 16384;
            #pragma unroll
            for (int ks = 0; ks < 2; ++ks) {
                bf16x8 af[4], bfr[4];
                #pragma unroll
                for (int i = 0; i < 4; ++i) {
                    const int row = wm * 64 + i * 16 + lrow;
                    const int gr = (ks * 4 + lk) ^ (row & 7);
                    af[i] = *reinterpret_cast<const bf16x8*>(Ab + row * 128 + gr * 16);
                }
                #pragma unroll
                for (int j = 0; j < 4; ++j) {
                    const int cl = wn * 64 + j * 16 + lrow;
                    const int gr = (ks * 4 + lk) ^ (cl & 7);
                    bfr[j] = *reinterpret_cast<const bf16x8*>(Bb + cl * 128 + gr * 16);
                }
                #pragma unroll
                for (int i = 0; i < 4; ++i)
                    #pragma unroll
                    for (int j = 0; j < 4; ++j)
                        acc[i][j] = __builtin_amdgcn_mfma_f32_16x16x32_bf16(
                            af[i], bfr[j], acc[i][j], 0, 0, 0);
            }
        }

        if (cc < 9) B_WRITE(nxt);
        __syncthreads();
    }

    // ---- norms ----
    atomicAdd(&qn[r], ss_tot);              // 4 threads per row r
    if (t < MROWS) {
        float s = 0.f;
        #pragma unroll
        for (int cc = 0; cc < 10; ++cc) s += pn_part[(size_t)(e * 10 + cc) * MROWS + t];
        pnl[t] = sqrtf(s);
    }
    __syncthreads();

    // ---- epilogue ----
    float nq4[4];
    int cl4[4];
    #pragma unroll
    for (int j = 0; j < 4; ++j) {
        cl4[j] = wn * 64 + j * 16 + lrow;
        nq4[j] = sqrtf(qn[cl4[j]]);
    }
    #pragma unroll
    for (int i = 0; i < 4; ++i) {
        #pragma unroll
        for (int rr = 0; rr < 4; ++rr) {
            const int nw = wm * 64 + i * 16 + lk * 4 + rr;   // D row
            if (nw < MROWS) {
                const float np_ = pnl[nw];
                const int w = nw / N_CNT, n = nw - w * N_CNT;
                #pragma unroll
                for (int j = 0; j < 4; ++j) {
                    const int qmj = qm0 + cl4[j];
                    if (qmj < QM_TOT) {
                        const int qq = qmj / N_CNT, mm = qmj - qq * N_CNT;
                        const float den = np_ * nq4[j] + 1e-8f;
                        out[(((size_t)(e * Q_CNT + qq) * W_CNT + w) * N_CNT + n) * N_CNT + mm] =
                            acc[i][j][rr] * __builtin_amdgcn_rcpf(den);
                    }
                }
            }
        }
    }
#undef A_ISSUE
#undef B_ISSUE
#undef B_WRITE
}

// ---------------- fallback (R2 kernel) if ws too small -----------------------
struct SMemFB {
    unsigned char A[256 * 128];
    unsigned char B[64 * 128];
    float ns[320];
};

__global__ __launch_bounds__(512, 4)
void sim_fallback_kernel(const float* __restrict__ proto,
                         const float* __restrict__ query,
                         float* __restrict__ out)
{
    __shared__ SMemFB smf;
    const int t = threadIdx.x;
    const int e = blockIdx.x / Q_CNT;
    const int q = blockIdx.x - e * Q_CNT;
    const float* pbase = proto + (size_t)e * (W_CNT * C_CNT * N_CNT);
    const float* qbase = query + ((size_t)e * Q_CNT + q) * (C_CNT * N_CNT);
    unsigned char* lds = (unsigned char*)&smf;
    if (t < 320) smf.ns[t] = 0.f;
    if (t < 208) {
        if (t < 88) *reinterpret_cast<f32x4*>(smf.A + 245 * 128 + t * 16) = (f32x4){0.f,0.f,0.f,0.f};
        else        *reinterpret_cast<f32x4*>(smf.B + 49 * 128 + (t - 88) * 16) = (f32x4){0.f,0.f,0.f,0.f};
    }
    const int nslot5 = (t < 304);
    const float* gp[5];
    int offidx[5];
    #pragma unroll
    for (int i = 0; i < 5; ++i) {
        gp[i] = pbase; offidx[i] = 0;
        if (i < 4 || nslot5) {
            const int s = t + i * 512;
            if (s < 1960) {
                const int kb = s / 245, nw = s - kb * 245;
                const int w = nw / 49, n = nw - w * 49;
                gp[i] = pbase + ((size_t)w * C_CNT + kb * 8) * N_CNT + n;
                offidx[i] = (nw * 128 + ((kb ^ (nw & 7)) << 4)) | (nw << 16);
            } else {
                const int s2 = s - 1960;
                const int kb = s2 / 49, mq = s2 - kb * 49;
                gp[i] = qbase + (size_t)(kb * 8) * N_CNT + mq;
                offidx[i] = (32768 + mq * 128 + ((kb ^ (mq & 7)) << 4)) | ((256 + mq) << 16);
            }
        }
    }
    float v[5][8];
    float ss[5] = {0.f,0.f,0.f,0.f,0.f};
    #pragma unroll
    for (int i = 0; i < 4; ++i)
        #pragma unroll
        for (int j = 0; j < 8; ++j) v[i][j] = gp[i][(size_t)j * N_CNT];
    if (nslot5)
        #pragma unroll
        for (int j = 0; j < 8; ++j) v[4][j] = gp[4][(size_t)j * N_CNT];
    f32x4 acc[2][4];
    #pragma unroll
    for (int i = 0; i < 2; ++i)
        #pragma unroll
        for (int j = 0; j < 4; ++j) acc[i][j] = (f32x4){0.f,0.f,0.f,0.f};
    const int wv = t >> 6, ln = t & 63, lrow = ln & 15, lk = ln >> 4;
    for (int kc = 0; kc < 10; ++kc) {
        #pragma unroll
        for (int i = 0; i < 5; ++i) {
            if (i < 4 || nslot5) {
                bf16x8 pk; float s8 = 0.f;
                #pragma unroll
                for (int j = 0; j < 8; ++j) { const float f = v[i][j]; s8 += f*f; pk[j] = f2bf(f); }
                ss[i] += s8;
                *reinterpret_cast<bf16x8*>(lds + (offidx[i] & 0xFFFF)) = pk;
            }
        }
        __syncthreads();
        if (kc < 9) {
            #pragma unroll
            for (int i = 0; i < 4; ++i) {
                gp[i] += 64 * N_CNT;
                #pragma unroll
                for (int j = 0; j < 8; ++j) v[i][j] = gp[i][(size_t)j * N_CNT];
            }
            if (nslot5) {
                gp[4] += 64 * N_CNT;
                #pragma unroll
                for (int j = 0; j < 8; ++j) v[4][j] = gp[4][(size_t)j * N_CNT];
            }
        }
        #pragma unroll
        for (int ks = 0; ks < 2; ++ks) {
            bf16x8 af[2], bfr[4];
            #pragma unroll
            for (int i = 0; i < 2; ++i) {
                const int row = (wv * 2 + i) * 16 + lrow;
                const int gr = (ks * 4 + lk) ^ (row & 7);
                af[i] = *reinterpret_cast<const bf16x8*>(lds + row * 128 + gr * 16);
            }
            #pragma unroll
            for (int j = 0; j < 4; ++j) {
                const int mq = j * 16 + lrow;
                const int gr = (ks * 4 + lk) ^ (mq & 7);
                bfr[j] = *reinterpret_cast<const bf16x8*>(lds + 32768 + mq * 128 + gr * 16);
            }
            #pragma unroll
            for (int i = 0; i < 2; ++i)
                #pragma unroll
                for (int j = 0; j < 4; ++j)
                    acc[i][j] = __builtin_amdgcn_mfma_f32_16x16x32_bf16(af[i], bfr[j], acc[i][j], 0, 0, 0);
        }
        __syncthreads();
    }
    #pragma unroll
    for (int i = 0; i < 5; ++i)
        if (i < 4 || nslot5) atomicAdd(&smf.ns[offidx[i] >> 16], ss[i]);
    __syncthreads();
    float nq[4];
    #pragma unroll
    for (int j = 0; j < 4; ++j) {
        const int mq = j * 16 + lrow;
        nq[j] = (mq < N_CNT) ? sqrtf(smf.ns[256 + mq]) : 1.f;
    }
    float* obase = out + (size_t)(e * Q_CNT + q) * (W_CNT * N_CNT * N_CNT);
    #pragma unroll
    for (int i = 0; i < 2; ++i) {
        #pragma unroll
        for (int rr = 0; rr < 4; ++rr) {
            const int nw = (wv * 2 + i) * 16 + lk * 4 + rr;
            if (nw < W_CNT * N_CNT) {
                const int w = nw / 49, n = nw - w * 49;
                const float np_ = sqrtf(smf.ns[nw]);
                float* orow = obase + ((size_t)w * N_CNT + n) * N_CNT;
                #pragma unroll
                for (int j = 0; j < 4; ++j) {
                    const int mq = j * 16 + lrow;
                    if (mq < N_CNT) orow[mq] = acc[i][j][rr] / (np_ * nq[j] + 1e-8f);
                }
            }
        }
    }
}

extern "C" void kernel_launch(void* const* d_in, const int* in_sizes, int n_in,
                              void* d_out, int out_size, void* d_ws, size_t ws_size,
                              hipStream_t stream)
{
    const float* proto = (const float*)d_in[0];
    const float* query = (const float*)d_in[1];
    float* out = (float*)d_out;

    if (ws_size < WS_NEEDED) {
        hipLaunchKernelGGL(sim_fallback_kernel, dim3(E_CNT * Q_CNT), dim3(512), 0, stream,
                           proto, query, out);
        return;
    }

    unsigned char* asw = (unsigned char*)d_ws;
    float* pn_part = (float*)((unsigned char*)d_ws + PN_OFF);

    hipLaunchKernelGGL(prep_kernel, dim3(E_CNT * 10), dim3(256), 0, stream,
                       proto, asw, pn_part);
    hipLaunchKernelGGL(gemm_kernel, dim3(E_CNT * NTILES), dim3(512), SM_BYTES, stream,
                       query, asw, pn_part, out);
}